// Round 9
// baseline (1124.417 us; speedup 1.0000x reference)
//
#include <hip/hip_runtime.h>
#include <math.h>

#define B_ 4
#define S_ 2048
#define D_ 512
#define H_ 8
#define DK_ 64
#define MROWS (B_ * S_)   // 8192

typedef short bf16x8 __attribute__((ext_vector_type(8)));
typedef float f32x4 __attribute__((ext_vector_type(4)));
typedef float f32x16 __attribute__((ext_vector_type(16)));

// fp32 -> bf16 RNE (proven rounds 3-11)
static __device__ __forceinline__ unsigned short f2bf(float x) {
    unsigned int u = __float_as_uint(x);
    return (unsigned short)((u + 0x7FFFu + ((u >> 16) & 1u)) >> 16);
}
static __device__ __forceinline__ float bf2f(unsigned short u) {
    return __uint_as_float((unsigned int)u << 16);
}
// packed fp32x2 -> bf16x2; operand->half mapping probed at runtime (r9-proven)
static __device__ __forceinline__ unsigned int cvt_pk_bf16(float a, float b) {
    unsigned int r;
    asm("v_cvt_pk_bf16_f32 %0, %1, %2" : "=v"(r) : "v"(a), "v"(b));
    return r;
}
static __device__ __forceinline__ float exp2_fast(float x) {
    float r;
    asm("v_exp_f32 %0, %1" : "=v"(r) : "v"(x));
    return r;
}
// async global->LDS DMA, 16B per lane; LDS dest is wave-uniform base + lane*16
static __device__ __forceinline__ void gld_lds16(const unsigned short* g, unsigned short* l) {
    __builtin_amdgcn_global_load_lds(
        (const __attribute__((address_space(1))) unsigned int*)g,
        (__attribute__((address_space(3))) unsigned int*)l, 16, 0, 0);
}
// v_permlane32_swap_b32: swaps a's upper 32 lanes with b's lower 32 lanes.
static __device__ __forceinline__ void plswap(unsigned int& a, unsigned int& b) {
    asm volatile("v_permlane32_swap_b32 %0, %1" : "+v"(a), "+v"(b));
}

#define NXE (MROWS * D_)        // 4194304 elems
#define NWE (D_ * D_)           // 262144 elems
#define CAST_BLOCKS ((3 * NXE + 2 * NWE) / 8 / 256)   // 6400
#define MASKE (B_ * S_ * S_)                          // 16777216 mask elems
#define MASK_BLOCKS (MASKE / 256 / 4)                 // 16384 (int mode: 4/thread)
#define MASKB_BYTE (MASKE / 256 / 16)                 // 4096 (byte mode: 16/thread)

// ---------------------------------------------------------------------------
// prep (r8-verbatim, passing): fused input cast + vectorized mask bit-pack.
// ---------------------------------------------------------------------------
__global__ __launch_bounds__(256) void prep(const float* __restrict__ Q,
                                            const float* __restrict__ K,
                                            const float* __restrict__ V,
                                            const float* __restrict__ Wq,
                                            const float* __restrict__ Wo,
                                            const void* __restrict__ mask,
                                            unsigned short* __restrict__ Qb,
                                            unsigned short* __restrict__ Kb,
                                            unsigned short* __restrict__ Vb,
                                            unsigned short* __restrict__ Wqb,
                                            unsigned short* __restrict__ Wob,
                                            unsigned long long* __restrict__ mb) {
    if (blockIdx.x < CAST_BLOCKS) {
        const int NA = NXE / 8;
        const int NWn = NWE / 8;
        int id = blockIdx.x * 256 + threadIdx.x;
        const float* src;
        unsigned short* dst;
        if (id < 3 * NA) {
            int a = id / NA, r = id - a * NA;
            src = (a == 0 ? Q : a == 1 ? K : V) + (size_t)r * 8;
            dst = (a == 0 ? Qb : a == 1 ? Kb : Vb) + (size_t)r * 8;
        } else {
            int r = id - 3 * NA;
            int a = r / NWn; r -= a * NWn;
            src = (a == 0 ? Wq : Wo) + (size_t)r * 8;
            dst = (a == 0 ? Wqb : Wob) + (size_t)r * 8;
        }
        float4 x = *(const float4*)src;
        float4 y = *(const float4*)(src + 4);
        unsigned short u[8] = {f2bf(x.x), f2bf(x.y), f2bf(x.z), f2bf(x.w),
                               f2bf(y.x), f2bf(y.y), f2bf(y.z), f2bf(y.w)};
        *(uint4*)dst = *(const uint4*)u;
    } else {
        const int mblk = blockIdx.x - CAST_BLOCKS;
        unsigned int accw = 0;
        if ((threadIdx.x & 63) == 0) {
            const unsigned int* mw0 = (const unsigned int*)mask;
            #pragma unroll
            for (int i = 0; i < 16; ++i) accw |= mw0[i];
        }
        accw = __shfl(accw, 0);
        const bool bytemode = (accw & 0xFFFFFF00u) != 0u;
        if (bytemode) {
            if (mblk >= MASKB_BYTE) return;
            const int gid = mblk * 256 + threadIdx.x;   // u16-piece index
            uint4 x = ((const uint4*)mask)[gid];
            unsigned int n[4];
            const unsigned int xs[4] = {x.x, x.y, x.z, x.w};
            #pragma unroll
            for (int i = 0; i < 4; ++i) {
                unsigned int y = xs[i];
                y |= y >> 4; y |= y >> 2; y |= y >> 1;
                y &= 0x01010101u;
                n[i] = (y * 0x01020408u) >> 24;
            }
            const unsigned short piece =
                (unsigned short)(n[0] | (n[1] << 4) | (n[2] << 8) | (n[3] << 12));
            ((unsigned short*)mb)[gid] = piece;
        } else {
            const int wid = (mblk * 256 + threadIdx.x) >> 6;
            const int lane = threadIdx.x & 63;
            const unsigned int* mi = (const unsigned int*)mask;
            const size_t base = (size_t)wid * 256;
            unsigned long long b0 = __ballot(mi[base + lane] != 0);
            unsigned long long b1 = __ballot(mi[base + 64 + lane] != 0);
            unsigned long long b2 = __ballot(mi[base + 128 + lane] != 0);
            unsigned long long b3 = __ballot(mi[base + 192 + lane] != 0);
            if (lane == 0) {
                const size_t wix = base >> 6;
                mb[wix] = b0; mb[wix + 1] = b1; mb[wix + 2] = b2; mb[wix + 3] = b3;
            }
        }
    }
}

// ---------------------------------------------------------------------------
// QKV projection v3 (r9-verbatim, passing): triple-buffered gload_lds staging
// with counted vmcnt.
// ---------------------------------------------------------------------------
__global__ __launch_bounds__(256) void proj3(const unsigned short* __restrict__ Qb,
                                             const unsigned short* __restrict__ Kb,
                                             const unsigned short* __restrict__ Vb,
                                             const unsigned short* __restrict__ Wqb,
                                             unsigned short* __restrict__ qs,
                                             unsigned short* __restrict__ kbo,
                                             unsigned short* __restrict__ vt) {
    __shared__ unsigned short smx[24576];   // 3 x [A 4096 | B 4096] shorts
    const int t = threadIdx.x;
    const int w = t >> 6, lane = t & 63, col = lane & 15, quad = lane >> 4;
    const int bm = blockIdx.x * 128, bn = blockIdx.y * 128;
    const int z = blockIdx.z;
    const unsigned short* X = (z == 0) ? Qb : (z == 1) ? Kb : Vb;
    const int wm = (w >> 1) * 64, wn = (w & 1) * 64;

    const int sr = w * 32 + (lane >> 2);
    const int ssw = (((lane & 3) ^ ((lane >> 3) & 3)) * 8);
    const unsigned short* ags = X + (size_t)(bm + sr) * D_ + ssw;
    const unsigned short* bgs = Wqb + (size_t)(bn + sr) * D_ + ssw;
    const int pseg = ((quad ^ ((col >> 1) & 3)) * 8);

    f32x4 acc[4][4];
    #pragma unroll
    for (int i = 0; i < 4; ++i)
        #pragma unroll
        for (int j = 0; j < 4; ++j) acc[i][j] = (f32x4){0.f, 0.f, 0.f, 0.f};

    #pragma unroll
    for (int s = 0; s < 2; ++s) {
        const int bb = s * 8192;
        gld_lds16(ags + s * 32, &smx[bb + w * 1024]);
        gld_lds16(ags + 16 * D_ + s * 32, &smx[bb + w * 1024 + 512]);
        gld_lds16(bgs + s * 32, &smx[bb + 4096 + w * 1024]);
        gld_lds16(bgs + 16 * D_ + s * 32, &smx[bb + 4096 + w * 1024 + 512]);
    }
    __asm__ __volatile__("s_waitcnt vmcnt(4)" ::: "memory");  // buf0 ready
    __builtin_amdgcn_s_barrier();

    #pragma unroll 1
    for (int ts = 0; ts < 16; ++ts) {
        if (ts + 2 < 16) {
            const int nb = ((ts + 2) % 3) * 8192;
            const int ko = (ts + 2) * 32;
            gld_lds16(ags + ko, &smx[nb + w * 1024]);
            gld_lds16(ags + 16 * D_ + ko, &smx[nb + w * 1024 + 512]);
            gld_lds16(bgs + ko, &smx[nb + 4096 + w * 1024]);
            gld_lds16(bgs + 16 * D_ + ko, &smx[nb + 4096 + w * 1024 + 512]);
        }
        __builtin_amdgcn_sched_barrier(0);

        const int cb = (ts % 3) * 8192;
        bf16x8 af[4], bg[4];
        #pragma unroll
        for (int i = 0; i < 4; ++i)
            af[i] = *(const bf16x8*)&smx[cb + (wm + i * 16 + col) * 32 + pseg];
        #pragma unroll
        for (int j = 0; j < 4; ++j)
            bg[j] = *(const bf16x8*)&smx[cb + 4096 + (wn + j * 16 + col) * 32 + pseg];
        #pragma unroll
        for (int i = 0; i < 4; ++i)
            #pragma unroll
            for (int j = 0; j < 4; ++j)
                acc[i][j] = __builtin_amdgcn_mfma_f32_16x16x32_bf16(
                    af[i], bg[j], acc[i][j], 0, 0, 0);

        if (ts < 14) {
            __asm__ __volatile__("s_waitcnt vmcnt(4)" ::: "memory");
        } else if (ts == 14) {
            __asm__ __volatile__("s_waitcnt vmcnt(0)" ::: "memory");
        }
        if (ts < 15) __builtin_amdgcn_s_barrier();
    }

    if (z == 2) {
        #pragma unroll
        for (int i = 0; i < 4; ++i) {
            const int R = bm + wm + i * 16 + quad * 4;
            const int bb = R >> 11, s0 = R & (S_ - 1);
            #pragma unroll
            for (int j = 0; j < 4; ++j) {
                const int C = bn + wn + j * 16 + col;
                const int hh = C >> 6, dd = C & (DK_ - 1);
                ushort4 u = make_ushort4(f2bf(acc[i][j][0]), f2bf(acc[i][j][1]),
                                         f2bf(acc[i][j][2]), f2bf(acc[i][j][3]));
                *(ushort4*)&vt[(((size_t)bb * H_ + hh) * DK_ + dd) * S_ + s0] = u;
            }
        }
    } else {
        unsigned short* O = (z == 0) ? qs : kbo;
        const float scl = (z == 0) ? 0.18033688f : 1.0f;  // 0.125 * log2(e)
        #pragma unroll
        for (int i = 0; i < 4; ++i)
            #pragma unroll
            for (int j = 0; j < 4; ++j) {
                const int R = bm + wm + i * 16 + quad * 4;
                const int C = bn + wn + j * 16 + col;
                #pragma unroll
                for (int r = 0; r < 4; ++r)
                    O[(size_t)(R + r) * D_ + C] = f2bf(acc[i][j][r] * scl);
            }
    }
}

// ---------------------------------------------------------------------------
// Output GEMM v4 (r10-verbatim, passing): fused combine, 2-or-4 partials.
// ---------------------------------------------------------------------------
__global__ __launch_bounds__(256) void gemm_out(const unsigned short* __restrict__ o0,
                                                const unsigned short* __restrict__ o1,
                                                const unsigned short* __restrict__ o2,
                                                const unsigned short* __restrict__ o3,
                                                const float* __restrict__ l0,
                                                const float* __restrict__ l1,
                                                const float* __restrict__ l2,
                                                const float* __restrict__ l3,
                                                const unsigned short* __restrict__ Wob,
                                                float* __restrict__ Out,
                                                const int np4) {
    __shared__ unsigned short smx[20480];  // A0@0 A1@4096 | B0@8192 B1@12288 B2@16384
    __shared__ float invt[128 * 8];        // [local row][head]
    const int t = threadIdx.x;
    const int w = t >> 6, lane = t & 63, col = lane & 15, quad = lane >> 4;
    const int bm = blockIdx.x * 128, bn = blockIdx.y * 128;
    const int wm = (w >> 1) * 64, wn = (w & 1) * 64;

    const int sr = w * 32 + (lane >> 2);
    const int ssw = (((lane & 3) ^ ((lane >> 3) & 3)) * 8);
    const size_t aoff = (size_t)(bm + sr) * D_ + ssw;
    const unsigned short* ag0 = o0 + aoff;
    const unsigned short* ag1 = o1 + aoff;
    const unsigned short* ag2 = o2 + aoff;
    const unsigned short* ag3 = o3 + aoff;
    const unsigned short* bgs = Wob + (size_t)(bn + sr) * D_ + ssw;
    const int pseg = ((quad ^ ((col >> 1) & 3)) * 8);

    f32x4 acc[4][4];
    #pragma unroll
    for (int i = 0; i < 4; ++i)
        #pragma unroll
        for (int j = 0; j < 4; ++j) acc[i][j] = (f32x4){0.f, 0.f, 0.f, 0.f};

    // ---- prologue: B-DMA(0); A-loads(0); B-DMA(1)  (vmcnt order matters) ---
    gld_lds16(bgs, &smx[8192 + w * 1024]);
    gld_lds16(bgs + 16 * D_, &smx[8192 + w * 1024 + 512]);
    uint4 p00 = *(const uint4*)(ag0);
    uint4 p01 = *(const uint4*)(ag1);
    uint4 p02, p03, p12, p13;
    if (np4) { p02 = *(const uint4*)(ag2); p03 = *(const uint4*)(ag3); }
    uint4 p10 = *(const uint4*)(ag0 + 16 * D_);
    uint4 p11 = *(const uint4*)(ag1 + 16 * D_);
    if (np4) { p12 = *(const uint4*)(ag2 + 16 * D_); p13 = *(const uint4*)(ag3 + 16 * D_); }
    gld_lds16(bgs + 32, &smx[12288 + w * 1024]);
    gld_lds16(bgs + 16 * D_ + 32, &smx[12288 + w * 1024 + 512]);

    // inv table: 1024 entries, 4/thread, exact fp32 division
    #pragma unroll
    for (int i = 0; i < 4; ++i) {
        const int e = t * 4 + i;
        const int row = bm + (e >> 3), hh = e & 7;
        float s = l0[(size_t)row * H_ + hh] + l1[(size_t)row * H_ + hh];
        if (np4) s += l2[(size_t)row * H_ + hh] + l3[(size_t)row * H_ + hh];
        invt[e] = 1.0f / s;
    }
    __asm__ __volatile__("s_waitcnt lgkmcnt(0)" ::: "memory");
    __builtin_amdgcn_s_barrier();   // invt visible (no vmcnt drain)

    // combine stage 0 -> A0
    {
        const float ivA = invt[sr * 8];           // stage 0 -> head 0
        const float ivB = invt[(sr + 16) * 8];
        const unsigned short* pa = (const unsigned short*)&p00;
        const unsigned short* pb = (const unsigned short*)&p01;
        const unsigned short* pc = (const unsigned short*)&p02;
        const unsigned short* pd = (const unsigned short*)&p03;
        unsigned short ob[8];
        #pragma unroll
        for (int i = 0; i < 8; ++i) {
            float fa = bf2f(pa[i]) + bf2f(pb[i]);
            if (np4) fa += bf2f(pc[i]) + bf2f(pd[i]);
            ob[i] = f2bf(fa * ivA);
        }
        *(uint4*)&smx[w * 1024 + lane * 8] = *(const uint4*)ob;
        pa = (const unsigned short*)&p10;
        pb = (const unsigned short*)&p11;
        pc = (const unsigned short*)&p12;
        pd = (const unsigned short*)&p13;
        #pragma unroll
        for (int i = 0; i < 8; ++i) {
            float fa = bf2f(pa[i]) + bf2f(pb[i]);
            if (np4) fa += bf2f(pc[i]) + bf2f(pd[i]);
            ob[i] = f2bf(fa * ivB);
        }
        *(uint4*)&smx[w * 1024 + 512 + lane * 8] = *(const uint4*)ob;
    }
    __asm__ __volatile__("s_waitcnt lgkmcnt(0)" ::: "memory");
    __builtin_amdgcn_s_barrier();   // A0 visible; B(1) still in flight

    #pragma unroll 1
    for (int ts = 0; ts < 16; ++ts) {
        uint4 a00, a01, a02, a03, a10, a11, a12, a13;
        const bool hasA = (ts + 1 < 16);
        if (hasA) {
            const int ko = (ts + 1) * 32;
            a00 = *(const uint4*)(ag0 + ko);
            a01 = *(const uint4*)(ag1 + ko);
            if (np4) { a02 = *(const uint4*)(ag2 + ko); a03 = *(const uint4*)(ag3 + ko); }
            a10 = *(const uint4*)(ag0 + 16 * D_ + ko);
            a11 = *(const uint4*)(ag1 + 16 * D_ + ko);
            if (np4) { a12 = *(const uint4*)(ag2 + 16 * D_ + ko); a13 = *(const uint4*)(ag3 + 16 * D_ + ko); }
        }
        if (ts + 2 < 16) {
            const int bb = 8192 + ((ts + 2) % 3) * 4096;
            const int ko = (ts + 2) * 32;
            gld_lds16(bgs + ko, &smx[bb + w * 1024]);
            gld_lds16(bgs + 16 * D_ + ko, &smx[bb + w * 1024 + 512]);
        }
        __builtin_amdgcn_sched_barrier(0);

        // compute step ts
        const int ab = (ts & 1) * 4096;
        const int bb = 8192 + (ts % 3) * 4096;
        bf16x8 af[4], bg[4];
        #pragma unroll
        for (int i = 0; i < 4; ++i)
            af[i] = *(const bf16x8*)&smx[ab + (wm + i * 16 + col) * 32 + pseg];
        #pragma unroll
        for (int j = 0; j < 4; ++j)
            bg[j] = *(const bf16x8*)&smx[bb + (wn + j * 16 + col) * 32 + pseg];
        #pragma unroll
        for (int i = 0; i < 4; ++i)
            #pragma unroll
            for (int j = 0; j < 4; ++j)
                acc[i][j] = __builtin_amdgcn_mfma_f32_16x16x32_bf16(
                    af[i], bg[j], acc[i][j], 0, 0, 0);

        if (hasA) {
            const int hh = (ts + 1) >> 1;
            const float ivA = invt[sr * 8 + hh];
            const float ivB = invt[(sr + 16) * 8 + hh];
            const int na = ((ts + 1) & 1) * 4096;
            const unsigned short* pa = (const unsigned short*)&a00;
            const unsigned short* pb = (const unsigned short*)&a01;
            const unsigned short* pc = (const unsigned short*)&a02;
            const unsigned short* pd = (const unsigned short*)&a03;
            unsigned short ob[8];
            #pragma unroll
            for (int i = 0; i < 8; ++i) {
                float fa = bf2f(pa[i]) + bf2f(pb[i]);
                if (np4) fa += bf2f(pc[i]) + bf2f(pd[i]);
                ob[i] = f2bf(fa * ivA);
            }
            *(uint4*)&smx[na + w * 1024 + lane * 8] = *(const uint4*)ob;
            pa = (const unsigned short*)&a10;
            pb = (const unsigned short*)&a11;
            pc = (const unsigned short*)&a12;
            pd = (const unsigned short*)&a13;
            #pragma unroll
            for (int i = 0; i < 8; ++i) {
                float fa = bf2f(pa[i]) + bf2f(pb[i]);
                if (np4) fa += bf2f(pc[i]) + bf2f(pd[i]);
                ob[i] = f2bf(fa * ivB);
            }
            *(uint4*)&smx[na + w * 1024 + 512 + lane * 8] = *(const uint4*)ob;
        }
        __asm__ __volatile__("s_waitcnt lgkmcnt(0)" ::: "memory");
        if (ts < 15) __builtin_amdgcn_s_barrier();
    }

    #pragma unroll
    for (int i = 0; i < 4; ++i)
        #pragma unroll
        for (int j = 0; j < 4; ++j) {
            const int R = bm + wm + i * 16 + quad * 4;
            const int C = bn + wn + j * 16 + col;
            #pragma unroll
            for (int r = 0; r < 4; ++r)
                Out[(size_t)(R + r) * D_ + C] = acc[i][j][r];
        }
}

// ---------------------------------------------------------------------------
// MFMA flash attention v8: KVBLK=32 -> LDS 16 KB -> 8 blocks/CU actually
// resident with the nspl=4 grid (2048 blocks = 8/CU; 8x16KB = 128KB < 160KB)
// = 8 waves/SIMD (was 4; v10 kept 32KB so residency never rose). Tiles of
// 32 k: K tile 32x64 / V tile 64x32 = ONE gld_lds16 each (2 DMAs/tile,
// vmcnt(3) steady, vmcnt(1) tail); mask is a u32/tile (cheaper shifts);
// kbi loop gone (pack/plswap mapping identical with slice=ksl). Masking
// applied AFTER exp2 (p = bit ? 0 : exp2(S)) to break the mask->exp dep.
// launch_bounds(256,8) pins VGPR<=64 for 8 waves/SIMD.
// ---------------------------------------------------------------------------
__global__ __launch_bounds__(256, 8) void attn_mfma(
        const unsigned short* __restrict__ qb,
        const unsigned short* __restrict__ kb,
        const unsigned short* __restrict__ vt,
        const unsigned long long* __restrict__ mb,
        unsigned short* __restrict__ o0,
        unsigned short* __restrict__ o1,
        unsigned short* __restrict__ o2,
        unsigned short* __restrict__ o3,
        float* __restrict__ l0,
        float* __restrict__ l1,
        float* __restrict__ l2,
        float* __restrict__ l3,
        const int nspl, const int klen) {
    __shared__ unsigned short sm[8192];   // buf0: K@0 V@2048 | buf1: K@4096 V@6144
    const int t = threadIdx.x;            // 0..255
    const int w = t >> 6;                 // wave 0..3
    const int lane = t & 63;
    const int q5 = lane & 31;
    const int hi = lane >> 5;
    const int h = blockIdx.y;
    const int kq = blockIdx.z % nspl;
    const int b = blockIdx.z / nspl;
    const int bh = b * H_ + h;
    const int qrow0 = blockIdx.x * 128 + w * 32;
    const int NT = klen >> 5;             // tiles of 32 k

    unsigned short* opart = (kq == 0) ? o0 : (kq == 1) ? o1 : (kq == 2) ? o2 : o3;
    float* lpart = (kq == 0) ? l0 : (kq == 1) ? l1 : (kq == 2) ? l2 : l3;

    const unsigned int chk = cvt_pk_bf16(1.0f, 2.0f);
    const bool ablow = ((chk & 0xFFFFu) == 0x3F80u);

    bf16x8 qf[4];
    {
        const unsigned short* qp =
            qb + (size_t)(b * S_ + qrow0 + q5) * D_ + h * DK_ + hi * 8;
        #pragma unroll
        for (int dsl = 0; dsl < 4; ++dsl)
            qf[dsl] = *(const bf16x8*)(qp + dsl * 16);
    }

    bf16x8 ones8;
    #pragma unroll
    for (int i = 0; i < 8; ++i) ones8[i] = (short)0x3F80;

    const float CREF = 8.656170245f;  // 6 * log2(e)
    f32x16 Oa, Ob, lacc, crefv;
    #pragma unroll
    for (int i = 0; i < 16; ++i) {
        Oa[i] = 0.f; Ob[i] = 0.f; lacc[i] = 0.f; crefv[i] = -CREF;
    }

    const int kbeg = kq * klen;

    // ---- DMA staging: K tile 32 rows x 8 segs (unit n=t: row n>>3, seg n&7,
    // fetch seg (n&7)^((n>>3)&7)); V tile 64 rows x 4 segs (row n>>2, seg n&3,
    // fetch seg (n&3)^((n>>2)&3)). One gld_lds16 per tile per array.
    const unsigned short* pK = kb
        + (size_t)(b * S_ + kbeg + (t >> 3)) * D_ + h * DK_
        + (((t & 7) ^ ((t >> 3) & 7)) * 8);
    const unsigned short* pV = vt
        + ((size_t)bh * DK_ + (t >> 2)) * S_ + kbeg
        + (((t & 3) ^ ((t >> 2) & 3)) * 8);

    // mask: one u32 per lane per 32k-tile
    const unsigned int* mbase32 = (const unsigned int*)mb
        + (size_t)(b * S_ + qrow0 + q5) * (S_ / 32) + (kbeg >> 5);

    // ---- prologue: stage tile 0 -> buf0 ------------------------------------
    gld_lds16(pK, &sm[w * 512]);
    gld_lds16(pV, &sm[2048 + w * 512]);
    pK += 32 * D_; pV += 32;

    const int x7 = (q5 & 7);              // K-read row-XOR (8-seg domain)
    const int x3 = (q5 & 3);              // V-read row-XOR (4-seg domain)

    #pragma unroll 1
    for (int ti = 0; ti < NT; ++ti) {
        unsigned int mw = mbase32[ti];
        __builtin_amdgcn_sched_barrier(0);
        if (ti < NT - 1) {
            const int nb = (ti & 1) ? 0 : 4096;
            gld_lds16(pK, &sm[nb + w * 512]);
            gld_lds16(pV, &sm[nb + 2048 + w * 512]);
            pK += 32 * D_; pV += 32;
            // outstanding: DMA(ti)x2 (oldest) + mask + DMA(ti+1)x2 -> retire 2
            __asm__ __volatile__("s_waitcnt vmcnt(3)" ::: "memory");
        } else {
            __asm__ __volatile__("s_waitcnt vmcnt(1)" ::: "memory");
        }
        __builtin_amdgcn_s_barrier();

        const int KB = (ti & 1) ? 4096 : 0;
        const int VB = KB + 2048;
        const unsigned int msh = mw >> (hi * 4);

        // S^T = mfma(A=K-frag, B=Q-frag), C-in = crefv (-CREF pre-applied)
        const int krow = KB + q5 * 64;
        __builtin_amdgcn_s_setprio(1);
        bf16x8 kf0 = *(const bf16x8*)&sm[krow + ((hi) ^ x7) * 8];
        f32x16 S = __builtin_amdgcn_mfma_f32_32x32x16_bf16(kf0, qf[0], crefv, 0, 0, 0);
        #pragma unroll
        for (int dsl = 1; dsl < 4; ++dsl) {
            bf16x8 kf = *(const bf16x8*)&sm[krow + (((dsl << 1) | hi) ^ x7) * 8];
            S = __builtin_amdgcn_mfma_f32_32x32x16_bf16(kf, qf[dsl], S, 0, 0, 0);
        }
        __builtin_amdgcn_s_setprio(0);

        // p = masked ? 0 : 2^(s' - CREF)   (mask applied after exp)
        float p[16];
        #pragma unroll
        for (int r = 0; r < 16; ++r) {
            const int c = (r & 3) + 8 * (r >> 2);
            p[r] = ((msh >> c) & 1u) ? 0.0f : exp2_fast(S[r]);
        }

        // pack + permlane32_swap -> 32x32x16 A-fragments; l + PV mfma
        #pragma unroll
        for (int ksl = 0; ksl < 2; ++ksl) {
            const int bsl = ksl * 8;
            unsigned int uA = ablow ? cvt_pk_bf16(p[bsl], p[bsl + 1])
                                    : cvt_pk_bf16(p[bsl + 1], p[bsl]);
            unsigned int uB = ablow ? cvt_pk_bf16(p[bsl + 2], p[bsl + 3])
                                    : cvt_pk_bf16(p[bsl + 3], p[bsl + 2]);
            unsigned int uC = ablow ? cvt_pk_bf16(p[bsl + 4], p[bsl + 5])
                                    : cvt_pk_bf16(p[bsl + 5], p[bsl + 4]);
            unsigned int uD = ablow ? cvt_pk_bf16(p[bsl + 6], p[bsl + 7])
                                    : cvt_pk_bf16(p[bsl + 7], p[bsl + 6]);
            plswap(uA, uC);
            plswap(uB, uD);
            union { unsigned int u[4]; bf16x8 v; } pa;
            pa.u[0] = uA; pa.u[1] = uB; pa.u[2] = uC; pa.u[3] = uD;

            const int vseg = (((ksl << 1) | hi) ^ x3) * 8;
            bf16x8 vf0 = *(const bf16x8*)&sm[VB + q5 * 32 + vseg];
            bf16x8 vf1 = *(const bf16x8*)&sm[VB + 1024 + q5 * 32 + vseg];
            __builtin_amdgcn_s_setprio(1);
            lacc = __builtin_amdgcn_mfma_f32_32x32x16_bf16(pa.v, ones8, lacc, 0, 0, 0);
            Oa = __builtin_amdgcn_mfma_f32_32x32x16_bf16(pa.v, vf0, Oa, 0, 0, 0);
            Ob = __builtin_amdgcn_mfma_f32_32x32x16_bf16(pa.v, vf1, Ob, 0, 0, 0);
            __builtin_amdgcn_s_setprio(0);
        }

        __builtin_amdgcn_s_barrier();
    }

    #pragma unroll
    for (int r = 0; r < 16; ++r) {
        const int qq = (r & 3) + 8 * (r >> 2) + 4 * hi;
        const size_t row = (size_t)(b * S_ + qrow0 + qq);
        opart[row * D_ + h * DK_ + q5]      = f2bf(Oa[r]);
        opart[row * D_ + h * DK_ + 32 + q5] = f2bf(Ob[r]);
        if (q5 == 0) lpart[row * H_ + h] = lacc[r];
    }
}

// ---------------------------------------------------------------------------
extern "C" void kernel_launch(void* const* d_in, const int* in_sizes, int n_in,
                              void* d_out, int out_size, void* d_ws, size_t ws_size,
                              hipStream_t stream) {
    const float* Q    = (const float*)d_in[0];
    const float* K    = (const float*)d_in[1];
    const float* V    = (const float*)d_in[2];
    const void*  mask = d_in[3];
    const float* Wq   = (const float*)d_in[4];
    const float* Wo   = (const float*)d_in[5];
    float* out = (float*)d_out;

    const size_t NX = (size_t)MROWS * D_;
    const size_t NW = (size_t)D_ * D_;
    unsigned short* Qb   = (unsigned short*)d_ws;   // bf16 input casts
    unsigned short* Kb   = Qb + NX;
    unsigned short* Vb   = Kb + NX;
    unsigned short* Wqb  = Vb + NX;
    unsigned short* Wob  = Wqb + NW;
    unsigned short* qbuf = Wob + NW;                // q proj * 0.125*log2e (bf16)
    unsigned short* kbuf = qbuf + NX;               // k proj (bf16 RM)
    unsigned short* vtb  = kbuf + NX;               // V^T (bf16)
    unsigned short* cbuf = vtb + NX;                // freed slot -> o2
    unsigned long long* mb = (unsigned long long*)(cbuf + NX);

    unsigned short* o0 = Qb;                        // overlay: partial O quarter 0
    unsigned short* o1 = Kb;                        // overlay: partial O quarter 1
    unsigned short* o2 = cbuf;                      // partial O quarter 2
    unsigned short* o3 = (unsigned short*)(mb + MASKE / 64);  // quarter 3 (fresh)
    float* l0 = (float*)Vb;                         // l partials (Vb slot, 1 MB)
    float* l1 = l0 + (size_t)MROWS * H_;
    float* l2 = l0 + 2 * (size_t)MROWS * H_;
    float* l3 = l0 + 3 * (size_t)MROWS * H_;

    // runtime gate: K-split x4 only if workspace covers o3
    const size_t need4 = (size_t)((char*)(o3 + NX) - (char*)d_ws);
    const int nspl = (ws_size >= need4) ? 4 : 2;

    prep<<<dim3(CAST_BLOCKS + MASK_BLOCKS), dim3(256), 0, stream>>>(
        Q, K, V, Wq, Wo, mask, Qb, Kb, Vb, Wqb, Wob, mb);

    proj3<<<dim3(MROWS / 128, D_ / 128, 3), dim3(256), 0, stream>>>(
        Qb, Kb, Vb, Wqb, qbuf, kbuf, vtb);

    attn_mfma<<<dim3(S_ / 128, H_, B_ * nspl), dim3(256), 0, stream>>>(
        qbuf, kbuf, vtb, mb, o0, o1, o2, o3, l0, l1, l2, l3, nspl, S_ / nspl);

    gemm_out<<<dim3(MROWS / 128, D_ / 128), dim3(256), 0, stream>>>(
        o0, o1, o2, o3, l0, l1, l2, l3, Wob, out, nspl == 4 ? 1 : 0);
}

// Round 10
// 243.228 us; speedup vs baseline: 4.6229x; 4.6229x over previous
//
#include <hip/hip_runtime.h>
#include <math.h>

#define B_ 4
#define S_ 2048
#define D_ 512
#define H_ 8
#define DK_ 64
#define MROWS (B_ * S_)   // 8192

typedef short bf16x8 __attribute__((ext_vector_type(8)));
typedef float f32x4 __attribute__((ext_vector_type(4)));
typedef float f32x16 __attribute__((ext_vector_type(16)));

// fp32 -> bf16 RNE (proven rounds 3-11)
static __device__ __forceinline__ unsigned short f2bf(float x) {
    unsigned int u = __float_as_uint(x);
    return (unsigned short)((u + 0x7FFFu + ((u >> 16) & 1u)) >> 16);
}
// packed fp32x2 -> bf16x2; operand->half mapping probed at runtime (r9-proven)
static __device__ __forceinline__ unsigned int cvt_pk_bf16(float a, float b) {
    unsigned int r;
    asm("v_cvt_pk_bf16_f32 %0, %1, %2" : "=v"(r) : "v"(a), "v"(b));
    return r;
}
static __device__ __forceinline__ float exp2_fast(float x) {
    float r;
    asm("v_exp_f32 %0, %1" : "=v"(r) : "v"(x));
    return r;
}
// async global->LDS DMA, 16B per lane; LDS dest is wave-uniform base + lane*16
static __device__ __forceinline__ void gld_lds16(const unsigned short* g, unsigned short* l) {
    __builtin_amdgcn_global_load_lds(
        (const __attribute__((address_space(1))) unsigned int*)g,
        (__attribute__((address_space(3))) unsigned int*)l, 16, 0, 0);
}
// v_permlane32_swap_b32: swaps a's upper 32 lanes with b's lower 32 lanes.
static __device__ __forceinline__ void plswap(unsigned int& a, unsigned int& b) {
    asm volatile("v_permlane32_swap_b32 %0, %1" : "+v"(a), "+v"(b));
}

#define NXE (MROWS * D_)        // 4194304 elems
#define NWE (D_ * D_)           // 262144 elems
#define CAST_BLOCKS ((3 * NXE + 2 * NWE) / 8 / 256)   // 6400
#define MASKE (B_ * S_ * S_)                          // 16777216 mask elems
#define MASK_BLOCKS (MASKE / 256 / 4)                 // 16384 (int mode: 4/thread)
#define MASKB_BYTE (MASKE / 256 / 16)                 // 4096 (byte mode: 16/thread)

// ---------------------------------------------------------------------------
// prep: fused input cast + VECTORIZED mask bit-pack (r6-verbatim, 245.4us).
// ---------------------------------------------------------------------------
__global__ __launch_bounds__(256) void prep(const float* __restrict__ Q,
                                            const float* __restrict__ K,
                                            const float* __restrict__ V,
                                            const float* __restrict__ Wq,
                                            const float* __restrict__ Wo,
                                            const void* __restrict__ mask,
                                            unsigned short* __restrict__ Qb,
                                            unsigned short* __restrict__ Kb,
                                            unsigned short* __restrict__ Vb,
                                            unsigned short* __restrict__ Wqb,
                                            unsigned short* __restrict__ Wob,
                                            unsigned long long* __restrict__ mb) {
    if (blockIdx.x < CAST_BLOCKS) {
        const int NA = NXE / 8;
        const int NWn = NWE / 8;
        int id = blockIdx.x * 256 + threadIdx.x;
        const float* src;
        unsigned short* dst;
        if (id < 3 * NA) {
            int a = id / NA, r = id - a * NA;
            src = (a == 0 ? Q : a == 1 ? K : V) + (size_t)r * 8;
            dst = (a == 0 ? Qb : a == 1 ? Kb : Vb) + (size_t)r * 8;
        } else {
            int r = id - 3 * NA;
            int a = r / NWn; r -= a * NWn;
            src = (a == 0 ? Wq : Wo) + (size_t)r * 8;
            dst = (a == 0 ? Wqb : Wob) + (size_t)r * 8;
        }
        float4 x = *(const float4*)src;
        float4 y = *(const float4*)(src + 4);
        unsigned short u[8] = {f2bf(x.x), f2bf(x.y), f2bf(x.z), f2bf(x.w),
                               f2bf(y.x), f2bf(y.y), f2bf(y.z), f2bf(y.w)};
        *(uint4*)dst = *(const uint4*)u;
    } else {
        const int mblk = blockIdx.x - CAST_BLOCKS;
        unsigned int accw = 0;
        if ((threadIdx.x & 63) == 0) {
            const unsigned int* mw0 = (const unsigned int*)mask;
            #pragma unroll
            for (int i = 0; i < 16; ++i) accw |= mw0[i];
        }
        accw = __shfl(accw, 0);
        const bool bytemode = (accw & 0xFFFFFF00u) != 0u;
        if (bytemode) {
            if (mblk >= MASKB_BYTE) return;
            const int gid = mblk * 256 + threadIdx.x;   // u16-piece index
            uint4 x = ((const uint4*)mask)[gid];
            unsigned int n[4];
            const unsigned int xs[4] = {x.x, x.y, x.z, x.w};
            #pragma unroll
            for (int i = 0; i < 4; ++i) {
                unsigned int y = xs[i];
                y |= y >> 4; y |= y >> 2; y |= y >> 1;
                y &= 0x01010101u;
                n[i] = (y * 0x01020408u) >> 24;   // b0|b1<<1|b2<<2|b3<<3
            }
            const unsigned short piece =
                (unsigned short)(n[0] | (n[1] << 4) | (n[2] << 8) | (n[3] << 12));
            ((unsigned short*)mb)[gid] = piece;
        } else {
            const int wid = (mblk * 256 + threadIdx.x) >> 6;
            const int lane = threadIdx.x & 63;
            const unsigned int* mi = (const unsigned int*)mask;
            const size_t base = (size_t)wid * 256;
            unsigned long long b0 = __ballot(mi[base + lane] != 0);
            unsigned long long b1 = __ballot(mi[base + 64 + lane] != 0);
            unsigned long long b2 = __ballot(mi[base + 128 + lane] != 0);
            unsigned long long b3 = __ballot(mi[base + 192 + lane] != 0);
            if (lane == 0) {
                const size_t wix = base >> 6;
                mb[wix] = b0; mb[wix + 1] = b1; mb[wix + 2] = b2; mb[wix + 3] = b3;
            }
        }
    }
}

// ---------------------------------------------------------------------------
// QKV projection v2 (r6-verbatim, 245.4us): gload_lds(16B) double-buffered
// staging with source-XOR swizzle; one vmcnt(0)+barrier per k-step.
// ---------------------------------------------------------------------------
__global__ __launch_bounds__(256) void proj3(const unsigned short* __restrict__ Qb,
                                             const unsigned short* __restrict__ Kb,
                                             const unsigned short* __restrict__ Vb,
                                             const unsigned short* __restrict__ Wqb,
                                             unsigned short* __restrict__ qs,
                                             unsigned short* __restrict__ kbo,
                                             unsigned short* __restrict__ vt) {
    __shared__ unsigned short smx[16384];
    const int t = threadIdx.x;
    const int w = t >> 6, lane = t & 63, col = lane & 15, quad = lane >> 4;
    const int bm = blockIdx.x * 128, bn = blockIdx.y * 128;
    const int z = blockIdx.z;
    const unsigned short* X = (z == 0) ? Qb : (z == 1) ? Kb : Vb;
    const int wm = (w >> 1) * 64, wn = (w & 1) * 64;

    const int sr = w * 32 + (lane >> 2);
    const int ssw = (((lane & 3) ^ ((lane >> 3) & 3)) * 8);
    const unsigned short* ags = X + (size_t)(bm + sr) * D_ + ssw;
    const unsigned short* bgs = Wqb + (size_t)(bn + sr) * D_ + ssw;
    const int pseg = ((quad ^ ((col >> 1) & 3)) * 8);

    f32x4 acc[4][4];
    #pragma unroll
    for (int i = 0; i < 4; ++i)
        #pragma unroll
        for (int j = 0; j < 4; ++j) acc[i][j] = (f32x4){0.f, 0.f, 0.f, 0.f};

    gld_lds16(ags, &smx[w * 1024]);
    gld_lds16(ags + 16 * D_, &smx[w * 1024 + 512]);
    gld_lds16(bgs, &smx[4096 + w * 1024]);
    gld_lds16(bgs + 16 * D_, &smx[4096 + w * 1024 + 512]);
    __asm__ __volatile__("s_waitcnt vmcnt(0)" ::: "memory");
    __builtin_amdgcn_s_barrier();

    int cur = 0;
    #pragma unroll 1
    for (int k0 = 0; k0 < D_; k0 += 32) {
        if (k0 + 32 < D_) {
            const int nb = (cur ^ 1) * 8192;
            gld_lds16(ags + k0 + 32, &smx[nb + w * 1024]);
            gld_lds16(ags + 16 * D_ + k0 + 32, &smx[nb + w * 1024 + 512]);
            gld_lds16(bgs + k0 + 32, &smx[nb + 4096 + w * 1024]);
            gld_lds16(bgs + 16 * D_ + k0 + 32, &smx[nb + 4096 + w * 1024 + 512]);
        }
        __builtin_amdgcn_sched_barrier(0);

        const int cb = cur * 8192;
        bf16x8 af[4], bg[4];
        #pragma unroll
        for (int i = 0; i < 4; ++i)
            af[i] = *(const bf16x8*)&smx[cb + (wm + i * 16 + col) * 32 + pseg];
        #pragma unroll
        for (int j = 0; j < 4; ++j)
            bg[j] = *(const bf16x8*)&smx[cb + 4096 + (wn + j * 16 + col) * 32 + pseg];
        #pragma unroll
        for (int i = 0; i < 4; ++i)
            #pragma unroll
            for (int j = 0; j < 4; ++j)
                acc[i][j] = __builtin_amdgcn_mfma_f32_16x16x32_bf16(
                    af[i], bg[j], acc[i][j], 0, 0, 0);

        __asm__ __volatile__("s_waitcnt vmcnt(0)" ::: "memory");
        __builtin_amdgcn_s_barrier();
        cur ^= 1;
    }

    if (z == 2) {
        #pragma unroll
        for (int i = 0; i < 4; ++i) {
            const int R = bm + wm + i * 16 + quad * 4;
            const int bb = R >> 11, s0 = R & (S_ - 1);
            #pragma unroll
            for (int j = 0; j < 4; ++j) {
                const int C = bn + wn + j * 16 + col;
                const int hh = C >> 6, dd = C & (DK_ - 1);
                ushort4 u = make_ushort4(f2bf(acc[i][j][0]), f2bf(acc[i][j][1]),
                                         f2bf(acc[i][j][2]), f2bf(acc[i][j][3]));
                *(ushort4*)&vt[(((size_t)bb * H_ + hh) * DK_ + dd) * S_ + s0] = u;
            }
        }
    } else {
        unsigned short* O = (z == 0) ? qs : kbo;
        const float scl = (z == 0) ? 0.18033688f : 1.0f;  // 0.125 * log2(e)
        #pragma unroll
        for (int i = 0; i < 4; ++i)
            #pragma unroll
            for (int j = 0; j < 4; ++j) {
                const int R = bm + wm + i * 16 + quad * 4;
                const int C = bn + wn + j * 16 + col;
                #pragma unroll
                for (int r = 0; r < 4; ++r)
                    O[(size_t)(R + r) * D_ + C] = f2bf(acc[i][j][r] * scl);
            }
    }
}

// ---------------------------------------------------------------------------
// Output GEMM v2 (r6-verbatim, 245.4us).
// ---------------------------------------------------------------------------
__global__ __launch_bounds__(256) void gemm_out(const unsigned short* __restrict__ Xb,
                                                const unsigned short* __restrict__ Wob,
                                                float* __restrict__ Out) {
    __shared__ unsigned short smx[16384];
    const int t = threadIdx.x;
    const int w = t >> 6, lane = t & 63, col = lane & 15, quad = lane >> 4;
    const int bm = blockIdx.x * 128, bn = blockIdx.y * 128;
    const int wm = (w >> 1) * 64, wn = (w & 1) * 64;

    const int sr = w * 32 + (lane >> 2);
    const int ssw = (((lane & 3) ^ ((lane >> 3) & 3)) * 8);
    const unsigned short* ags = Xb + (size_t)(bm + sr) * D_ + ssw;
    const unsigned short* bgs = Wob + (size_t)(bn + sr) * D_ + ssw;
    const int pseg = ((quad ^ ((col >> 1) & 3)) * 8);

    f32x4 acc[4][4];
    #pragma unroll
    for (int i = 0; i < 4; ++i)
        #pragma unroll
        for (int j = 0; j < 4; ++j) acc[i][j] = (f32x4){0.f, 0.f, 0.f, 0.f};

    gld_lds16(ags, &smx[w * 1024]);
    gld_lds16(ags + 16 * D_, &smx[w * 1024 + 512]);
    gld_lds16(bgs, &smx[4096 + w * 1024]);
    gld_lds16(bgs + 16 * D_, &smx[4096 + w * 1024 + 512]);
    __asm__ __volatile__("s_waitcnt vmcnt(0)" ::: "memory");
    __builtin_amdgcn_s_barrier();

    int cur = 0;
    #pragma unroll 1
    for (int k0 = 0; k0 < D_; k0 += 32) {
        if (k0 + 32 < D_) {
            const int nb = (cur ^ 1) * 8192;
            gld_lds16(ags + k0 + 32, &smx[nb + w * 1024]);
            gld_lds16(ags + 16 * D_ + k0 + 32, &smx[nb + w * 1024 + 512]);
            gld_lds16(bgs + k0 + 32, &smx[nb + 4096 + w * 1024]);
            gld_lds16(bgs + 16 * D_ + k0 + 32, &smx[nb + 4096 + w * 1024 + 512]);
        }
        __builtin_amdgcn_sched_barrier(0);

        const int cb = cur * 8192;
        bf16x8 af[4], bg[4];
        #pragma unroll
        for (int i = 0; i < 4; ++i)
            af[i] = *(const bf16x8*)&smx[cb + (wm + i * 16 + col) * 32 + pseg];
        #pragma unroll
        for (int j = 0; j < 4; ++j)
            bg[j] = *(const bf16x8*)&smx[cb + 4096 + (wn + j * 16 + col) * 32 + pseg];
        #pragma unroll
        for (int i = 0; i < 4; ++i)
            #pragma unroll
            for (int j = 0; j < 4; ++j)
                acc[i][j] = __builtin_amdgcn_mfma_f32_16x16x32_bf16(
                    af[i], bg[j], acc[i][j], 0, 0, 0);

        __asm__ __volatile__("s_waitcnt vmcnt(0)" ::: "memory");
        __builtin_amdgcn_s_barrier();
        cur ^= 1;
    }

    #pragma unroll
    for (int i = 0; i < 4; ++i)
        #pragma unroll
        for (int j = 0; j < 4; ++j) {
            const int R = bm + wm + i * 16 + quad * 4;
            const int C = bn + wn + j * 16 + col;
            #pragma unroll
            for (int r = 0; r < 4; ++r)
                Out[(size_t)(R + r) * D_ + C] = acc[i][j][r];
        }
}

// ---------------------------------------------------------------------------
// MFMA flash attention v6c (r6-verbatim, 245.4us): all-32x32x16 pipeline,
// register-P via cvt_pk+permlane32_swap, crefv accumulator-bake, K/V DMA
// double-buffered with counted vmcnt, 32KB LDS, 4 blocks/CU.
// NOTE (r11 lesson): occupancy is REGISTER-bound (~112 unified regs live:
// 48 AGPR acc + crefv + qf + p[16]); launch_bounds >4 waves/SIMD forces
// accumulator spill-to-scratch (1015us, FETCH 1.67GB). Do not raise.
// ---------------------------------------------------------------------------
__global__ __launch_bounds__(256, 4) void attn_mfma(
        const unsigned short* __restrict__ qb,
        const unsigned short* __restrict__ kb,
        const unsigned short* __restrict__ vt,
        const unsigned long long* __restrict__ mb,
        unsigned short* __restrict__ o0,
        unsigned short* __restrict__ o1,
        float* __restrict__ l0,
        float* __restrict__ l1) {
    __shared__ unsigned short sm[16384];
    const int t = threadIdx.x;            // 0..255
    const int w = t >> 6;                 // wave 0..3
    const int lane = t & 63;
    const int q5 = lane & 31;
    const int hi = lane >> 5;
    const int h = blockIdx.y;
    const int b = blockIdx.z >> 1;
    const int khalf = blockIdx.z & 1;
    const int bh = b * H_ + h;
    const int qrow0 = blockIdx.x * 128 + w * 32;

    unsigned short* opart = khalf ? o1 : o0;
    float* lpart = khalf ? l1 : l0;

    const unsigned int chk = cvt_pk_bf16(1.0f, 2.0f);
    const bool ablow = ((chk & 0xFFFFu) == 0x3F80u);

    bf16x8 qf[4];
    {
        const unsigned short* qp =
            qb + (size_t)(b * S_ + qrow0 + q5) * D_ + h * DK_ + hi * 8;
        #pragma unroll
        for (int dsl = 0; dsl < 4; ++dsl)
            qf[dsl] = *(const bf16x8*)(qp + dsl * 16);
    }

    bf16x8 ones8;
    #pragma unroll
    for (int i = 0; i < 8; ++i) ones8[i] = (short)0x3F80;

    const float CREF = 8.656170245f;  // 6 * log2(e)
    f32x16 Oa, Ob, lacc, crefv;
    #pragma unroll
    for (int i = 0; i < 16; ++i) {
        Oa[i] = 0.f; Ob[i] = 0.f; lacc[i] = 0.f; crefv[i] = -CREF;
    }

    const int kbeg = khalf * (S_ / 2);

    const int ln8 = lane >> 3;
    const int fs8 = ((lane & 7) ^ ln8) * 8;
    const int r0 = w * 16 + ln8;
    const unsigned short* pK0 = kb + (size_t)(b * S_ + kbeg + r0) * D_ + h * DK_ + fs8;
    const unsigned short* pK1 = pK0 + 8 * D_;
    const unsigned short* pV0 = vt + ((size_t)bh * DK_ + r0) * S_ + kbeg + fs8;
    const unsigned short* pV1 = pV0 + 8 * S_;

    const unsigned long long* mbase =
        mb + (size_t)(b * S_ + qrow0 + q5) * (S_ / 64) + (kbeg >> 6);

    gld_lds16(pK0, &sm[w * 1024]);
    gld_lds16(pK1, &sm[w * 1024 + 512]);
    gld_lds16(pV0, &sm[4096 + w * 1024]);
    gld_lds16(pV1, &sm[4096 + w * 1024 + 512]);
    pK0 += 64 * D_; pK1 += 64 * D_; pV0 += 64; pV1 += 64;

    const int x7 = (q5 & 7);

    #pragma unroll 1
    for (int ti = 0; ti < 16; ++ti) {
        unsigned long long mw = mbase[ti];
        __builtin_amdgcn_sched_barrier(0);
        if (ti < 15) {
            const int nb = (ti & 1) ? 0 : 8192;
            gld_lds16(pK0, &sm[nb + w * 1024]);
            gld_lds16(pK1, &sm[nb + w * 1024 + 512]);
            gld_lds16(pV0, &sm[nb + 4096 + w * 1024]);
            gld_lds16(pV1, &sm[nb + 4096 + w * 1024 + 512]);
            pK0 += 64 * D_; pK1 += 64 * D_; pV0 += 64; pV1 += 64;
            __asm__ __volatile__("s_waitcnt vmcnt(5)" ::: "memory");
        } else {
            __asm__ __volatile__("s_waitcnt vmcnt(1)" ::: "memory");
        }
        __builtin_amdgcn_s_barrier();

        const int KB = (ti & 1) ? 8192 : 0;
        const int VB = KB + 4096;
        const unsigned long long msh = mw >> (hi * 4);

        #pragma unroll
        for (int kbi = 0; kbi < 2; ++kbi) {
            const int krow = KB + (kbi * 32 + q5) * 64;
            __builtin_amdgcn_s_setprio(1);
            bf16x8 kf0 = *(const bf16x8*)&sm[krow + ((hi) ^ x7) * 8];
            f32x16 S = __builtin_amdgcn_mfma_f32_32x32x16_bf16(kf0, qf[0], crefv, 0, 0, 0);
            #pragma unroll
            for (int dsl = 1; dsl < 4; ++dsl) {
                bf16x8 kf = *(const bf16x8*)&sm[krow + (((dsl << 1) | hi) ^ x7) * 8];
                S = __builtin_amdgcn_mfma_f32_32x32x16_bf16(kf, qf[dsl], S, 0, 0, 0);
            }
            __builtin_amdgcn_s_setprio(0);

            float p[16];
            #pragma unroll
            for (int r = 0; r < 16; ++r) {
                const int c = kbi * 32 + (r & 3) + 8 * (r >> 2);
                const bool msk = ((msh >> c) & 1ull) != 0ull;
                p[r] = exp2_fast(msk ? -1e30f : S[r]);
            }

            #pragma unroll
            for (int ksl = 0; ksl < 2; ++ksl) {
                const int bsl = ksl * 8;
                unsigned int uA = ablow ? cvt_pk_bf16(p[bsl], p[bsl + 1])
                                        : cvt_pk_bf16(p[bsl + 1], p[bsl]);
                unsigned int uB = ablow ? cvt_pk_bf16(p[bsl + 2], p[bsl + 3])
                                        : cvt_pk_bf16(p[bsl + 3], p[bsl + 2]);
                unsigned int uC = ablow ? cvt_pk_bf16(p[bsl + 4], p[bsl + 5])
                                        : cvt_pk_bf16(p[bsl + 5], p[bsl + 4]);
                unsigned int uD = ablow ? cvt_pk_bf16(p[bsl + 6], p[bsl + 7])
                                        : cvt_pk_bf16(p[bsl + 7], p[bsl + 6]);
                plswap(uA, uC);
                plswap(uB, uD);
                union { unsigned int u[4]; bf16x8 v; } pa;
                pa.u[0] = uA; pa.u[1] = uB; pa.u[2] = uC; pa.u[3] = uD;

                const int slice = kbi * 2 + ksl;
                const int vseg = (((slice << 1) | hi) ^ x7) * 8;
                bf16x8 vf0 = *(const bf16x8*)&sm[VB + q5 * 64 + vseg];
                bf16x8 vf1 = *(const bf16x8*)&sm[VB + (32 + q5) * 64 + vseg];
                __builtin_amdgcn_s_setprio(1);
                lacc = __builtin_amdgcn_mfma_f32_32x32x16_bf16(pa.v, ones8, lacc, 0, 0, 0);
                Oa = __builtin_amdgcn_mfma_f32_32x32x16_bf16(pa.v, vf0, Oa, 0, 0, 0);
                Ob = __builtin_amdgcn_mfma_f32_32x32x16_bf16(pa.v, vf1, Ob, 0, 0, 0);
                __builtin_amdgcn_s_setprio(0);
            }
        }

        __builtin_amdgcn_s_barrier();
    }

    #pragma unroll
    for (int r = 0; r < 16; ++r) {
        const int qq = (r & 3) + 8 * (r >> 2) + 4 * hi;
        const size_t row = (size_t)(b * S_ + qrow0 + qq);
        opart[row * D_ + h * DK_ + q5]      = f2bf(Oa[r]);
        opart[row * D_ + h * DK_ + 32 + q5] = f2bf(Ob[r]);
        if (q5 == 0) lpart[row * H_ + h] = lacc[r];
    }
}

// ---------------------------------------------------------------------------
// combine: cbuf = (O0 + O1) / (l0 + l1), bf16 out. 8 elems/thread.
// ---------------------------------------------------------------------------
__global__ __launch_bounds__(256) void combine(const unsigned short* __restrict__ o0,
                                               const unsigned short* __restrict__ o1,
                                               const float* __restrict__ l0,
                                               const float* __restrict__ l1,
                                               unsigned short* __restrict__ cb) {
    const int id = blockIdx.x * 256 + threadIdx.x;   // 0 .. NXE/8-1
    const size_t base = (size_t)id * 8;
    const int row = (int)(base >> 9);                // /D_
    const int hh = ((int)base & (D_ - 1)) >> 6;
    uint4 ua = *(const uint4*)(o0 + base);
    uint4 ub = *(const uint4*)(o1 + base);
    const float inv = 1.0f / (l0[(size_t)row * H_ + hh] + l1[(size_t)row * H_ + hh]);
    const unsigned short* pa = (const unsigned short*)&ua;
    const unsigned short* pb = (const unsigned short*)&ub;
    unsigned short out[8];
    #pragma unroll
    for (int i = 0; i < 8; ++i) {
        float fa = __uint_as_float((unsigned int)pa[i] << 16);
        float fb = __uint_as_float((unsigned int)pb[i] << 16);
        out[i] = f2bf((fa + fb) * inv);
    }
    *(uint4*)(cb + base) = *(const uint4*)out;
}

// ---------------------------------------------------------------------------
extern "C" void kernel_launch(void* const* d_in, const int* in_sizes, int n_in,
                              void* d_out, int out_size, void* d_ws, size_t ws_size,
                              hipStream_t stream) {
    const float* Q    = (const float*)d_in[0];
    const float* K    = (const float*)d_in[1];
    const float* V    = (const float*)d_in[2];
    const void*  mask = d_in[3];
    const float* Wq   = (const float*)d_in[4];
    const float* Wo   = (const float*)d_in[5];
    float* out = (float*)d_out;

    const size_t NX = (size_t)MROWS * D_;
    const size_t NW = (size_t)D_ * D_;
    unsigned short* Qb   = (unsigned short*)d_ws;   // bf16 input casts
    unsigned short* Kb   = Qb + NX;
    unsigned short* Vb   = Kb + NX;
    unsigned short* Wqb  = Vb + NX;
    unsigned short* Wob  = Wqb + NW;
    unsigned short* qbuf = Wob + NW;                // q proj * 0.125*log2e (bf16)
    unsigned short* kbuf = qbuf + NX;               // k proj (bf16 RM)
    unsigned short* vtb  = kbuf + NX;               // V^T (bf16)
    unsigned short* cbuf = vtb + NX;                // context (bf16 RM)
    unsigned long long* mb = (unsigned long long*)(cbuf + NX);

    unsigned short* o0 = Qb;                        // overlay: partial O half 0
    unsigned short* o1 = Kb;                        // overlay: partial O half 1
    float* l0 = (float*)Vb;                         // overlay: partial l half 0
    float* l1 = l0 + (size_t)MROWS * H_;            // partial l half 1

    prep<<<dim3(CAST_BLOCKS + MASK_BLOCKS), dim3(256), 0, stream>>>(
        Q, K, V, Wq, Wo, mask, Qb, Kb, Vb, Wqb, Wob, mb);

    proj3<<<dim3(MROWS / 128, D_ / 128, 3), dim3(256), 0, stream>>>(
        Qb, Kb, Vb, Wqb, qbuf, kbuf, vtb);

    attn_mfma<<<dim3(S_ / 128, H_, B_ * 2), dim3(256), 0, stream>>>(
        qbuf, kbuf, vtb, mb, o0, o1, l0, l1);

    combine<<<dim3((int)(NX / 8 / 256)), dim3(256), 0, stream>>>(o0, o1, l0, l1, cbuf);

    gemm_out<<<dim3(MROWS / 128, D_ / 128), dim3(256), 0, stream>>>(cbuf, Wob, out);
}